// Round 22
// baseline (79.523 us; speedup 1.0000x reference)
//
#include <hip/hip_runtime.h>
#include <stdint.h>

#define KK 5
#define SCALE_F 50000.0f
#define OC 128
#define IC 128
#define HH 56
#define WW 56
#define NB 64
#define HWSZ (HH * WW)          // 3136
#define NTAP 9
#define NWEL (OC * IC * NTAP)   // 147456

// ---- MFMA path geometry ----
#define PD 58                   // padded spatial dim
#define NICQ 8                  // 16-byte ic-chunks per pixel (128 ic)
// apk8 chunk index: ((n*PD + hh)*NICQ + icq)*PD + ww ; byte addr = chunk*16
// bfrag chunk index: (kk*4 + oct)*64 + lane   (kk = icb*9 + tap)

// ---- bitplane fallback geometry (verified R5) ----
#define PW 60
#define PROWS 58
#define PLANE (PROWS * PW)      // 3480
#define PLSTRIDE (NB * PLANE)   // 222720
#define OCPB 2
#define WPT 4

typedef int v4i  __attribute__((ext_vector_type(4)));
typedef int v16i __attribute__((ext_vector_type(16)));

__device__ __forceinline__ constexpr int koff2(int kk) {
    int icb = kk / 9, tap = kk % 9;
    int dh = tap / 3 - 1, dw = tap % 3 - 1;
    return (dh * NICQ + icb * 2) * PD + dw;
}

// ===========================================================================
// ============================ MFMA (primary) path ==========================
// ===========================================================================

// Kernel 0: zero the padded borders of apk8 (1824 chunks per n).
__global__ void __launch_bounds__(256) border_kernel(int8_t* __restrict__ apk8) {
    int j = blockIdx.x * 256 + threadIdx.x;       // < 64*1824 = 116736
    int n  = j / 1824;
    int rj = j - n * 1824;
    int hh, icq, ww;
    if (rj < 928) {                                // rows 0 and 57
        hh = (rj / 464) * 57;
        int q = rj % 464;
        icq = q / PD;
        ww  = q - icq * PD;
    } else {                                       // cols 0 and 57, rows 1..56
        int q = rj - 928;                          // < 896
        hh = 1 + (q >> 4);
        int r2 = q & 15;
        icq = r2 >> 1;
        ww  = (r2 & 1) * 57;
    }
    size_t chunk = (((size_t)n * PD + hh) * NICQ + icq) * PD + ww;
    *(int4*)(apk8 + chunk * 16) = make_int4(0, 0, 0, 0);
}

// Kernel 1: SDP weight gen + binarize; int8 +-1 in MFMA B-fragment order.
__global__ void __launch_bounds__(256) wpack_kernel(
    const float* __restrict__ M, const float* __restrict__ Z,
    const float* __restrict__ rv, int8_t* __restrict__ bfrag) {
    int i = blockIdx.x * 256 + threadIdx.x;       // < 147456
    int oc = i / 1152;
    int r1 = i - oc * 1152;
    int ic = r1 / 9;
    int tap = r1 - ic * 9;

    float m  = M[i];
    float z0 = Z[0 * NWEL + i];
    float z1 = Z[1 * NWEL + i];
    float z2 = Z[2 * NWEL + i];
    float z3 = Z[3 * NWEL + i];
    float z4 = Z[4 * NWEL + i];
    float s  = z0 * z0 + z1 * z1 + z2 * z2 + z3 * z3 + z4 * z4;
    float A  = m * m + s * (1.0f / SCALE_F);
    float inv = 1.0f / sqrtf(A);
    float w = rv[0] * (z0 * inv);
    w += rv[1] * (z1 * inv);
    w += rv[2] * (z2 * inv);
    w += rv[3] * (z3 * inv);
    w += rv[4] * (z4 * inv);
    w += m * inv;

    int8_t sv = (w > 0.0f) ? (int8_t)1 : (int8_t)-1;
    int icb = ic >> 5, khalf = (ic >> 4) & 1, b = ic & 15;
    int kk  = icb * 9 + tap;                      // K order matches bconv
    int oct = oc >> 5;
    int lane = khalf * 32 + (oc & 31);
    bfrag[(size_t)((kk * 4 + oct) * 64 + lane) * 16 + b] = sv;
}

// Kernel 2: binarize f32 NCHW -> int8 chunked layout [n][hh][icq][ww][16].
__global__ void __launch_bounds__(448) apack_kernel(
    const float* __restrict__ x, int8_t* __restrict__ apk8) {
    int h = blockIdx.x;           // 0..55
    int n = blockIdx.y;           // 0..63
    int t = threadIdx.x;          // 0..447
    int w   = t % 56;
    int icq = t / 56;             // 0..7
    const float* xp = x + ((size_t)n * IC + icq * 16) * HWSZ + h * WW + w;

    uint32_t pk[4];
#pragma unroll
    for (int g = 0; g < 4; ++g) {
        uint32_t v = 0;
#pragma unroll
        for (int j = 0; j < 4; ++j) {
            float f = xp[(size_t)(g * 4 + j) * HWSZ];
            uint32_t sel = (f > 0.0f) ? 0x01u : 0xFFu;
            v |= sel << (8 * j);
        }
        pk[g] = v;
    }
    size_t chunk = (((size_t)n * PD + (h + 1)) * NICQ + icq) * PD + (w + 1);
    *(uint4*)(apk8 + chunk * 16) = make_uint4(pk[0], pk[1], pk[2], pk[3]);
}

// A-load via inline asm: INVISIBLE to the compiler's waitcnt tracker, so the
// only waits in the K-loop are OUR counted vmcnt(N) (AITER pattern, T4).
#define ALOAD(dst, ab, slot, kkp)                                            \
    asm volatile("global_load_dwordx4 %0, %1, off"                           \
                 : "=v"(dst[slot])                                           \
                 : "v"((uint64_t)(uintptr_t)(apk8 + ((size_t)((ab) + koff2(kkp)) << 4))))

// Kernel 3: implicit-GEMM conv — [2px x 2oc] tile + COUNTED VMCNT (R12+R21).
// grid = 784 (392 px-blocks x 2 oc-halves, exact), block = 512 thr = 8 waves.
// Wave = 64 px x 64 oc: acc[2][2] (64 regs), 4 MFMA per (2 A + 2 B) loads —
// HALF the per-MFMA load cost and HALF total LDS traffic (462 vs 924 MB) of
// the R19/R21 [1x2] tile. A = inline-asm loads, ring-3, issued BEFORE the
// counted wait -> 4 ops stay in flight (steady vmcnt(4), tail 2->0), with
// sched_barrier(0) fencing MFMA below the wait (rule #18). B = ring-2
// compiler-tracked ds_reads. Zero K-loop barriers. ~122 VGPR, lb(512,4).
__global__ void __launch_bounds__(512, 4) bconv_kernel(
    const int8_t* __restrict__ apk8, const int8_t* __restrict__ bfrag,
    const float* __restrict__ alpha, float* __restrict__ out) {
    __shared__ uint4 ldsB[4608];   // [kk36][j2][lane64], 73,728 B

    int tx = threadIdx.x;
    int lane = tx & 63, wid = tx >> 6;        // wid 0..7
    int half = lane >> 5, l31 = lane & 31;

    // bijective XCD swizzle (784 = 8 * 98); och pairs colocate per XCD
    int bid = blockIdx.x;
    int swz = (bid & 7) * 98 + (bid >> 3);     // 0..783
    int och = swz & 1;
    int pxb = swz >> 1;                        // 0..391
    int ocb = och * 64;

    int ab[2]; size_t ob[2];
#pragma unroll
    for (int tm = 0; tm < 2; ++tm) {
        int px = pxb * 512 + wid * 64 + tm * 32 + l31;   // < 200704 exactly
        int n  = px / HWSZ;
        int hw = px - n * HWSZ;
        int h  = hw / WW;
        int w  = hw - h * WW;
        ab[tm] = ((n * PD + h + 1) * NICQ + half) * PD + (w + 1);
        ob[tm] = (size_t)n * OC * HWSZ + hw + (size_t)half * HWSZ;
    }
    int ab0 = ab[0], ab1 = ab[1];

    // ---- A ring-3: issue kk=0,1 pairs BEFORE B staging (latency overlap) ----
    v4i ar0[3], ar1[3];
    ALOAD(ar0, ab0, 0, 0); ALOAD(ar1, ab1, 0, 0);
    ALOAD(ar0, ab0, 1, 1); ALOAD(ar1, ab1, 1, 1);

    // ---- stage B-half once: 4608 chunks, 9 per thread, coalesced ----
    const uint4* gB = (const uint4*)bfrag;
#pragma unroll
    for (int s = 0; s < 9; ++s) {
        int idx = tx + s * 512;
        int kk = idx >> 7, j = (idx >> 6) & 1, ln = idx & 63;
        ldsB[idx] = gB[((kk << 2) + (och << 1) + j) * 64 + ln];
    }
    __syncthreads();   // drains staging (and our prologue loads land too)

    // ---- B ring-2: preload kk = 0 ----
    v4i b0r[2], b1r[2];
    b0r[0] = *(const v4i*)&ldsB[0 * 128 + lane];
    b1r[0] = *(const v4i*)&ldsB[0 * 128 + 64 + lane];

    v16i acc00 = {}, acc01 = {}, acc10 = {}, acc11 = {};
#pragma unroll
    for (int kk = 0; kk < 36; ++kk) {
        if (kk + 2 < 36) {                     // issue A pair kk+2 (before wait)
            ALOAD(ar0, ab0, (kk + 2) % 3, kk + 2);
            ALOAD(ar1, ab1, (kk + 2) % 3, kk + 2);
        }
        // counted wait: pair kk guaranteed done; pairs kk+1,kk+2 stay in flight
        if (kk <= 33)      asm volatile("s_waitcnt vmcnt(4)");
        else if (kk == 34) asm volatile("s_waitcnt vmcnt(2)");
        else               asm volatile("s_waitcnt vmcnt(0)");
        __builtin_amdgcn_sched_barrier(0);     // rule #18: no MFMA above wait

        if (kk + 1 < 36) {                     // B prefetch, 1 ahead (compiler)
            b0r[(kk + 1) & 1] = *(const v4i*)&ldsB[(kk + 1) * 128 + lane];
            b1r[(kk + 1) & 1] = *(const v4i*)&ldsB[(kk + 1) * 128 + 64 + lane];
        }
        v4i A0 = ar0[kk % 3], A1 = ar1[kk % 3];
        v4i B0 = b0r[kk & 1], B1 = b1r[kk & 1];
        acc00 = __builtin_amdgcn_mfma_i32_32x32x32_i8(A0, B0, acc00, 0, 0, 0);
        acc01 = __builtin_amdgcn_mfma_i32_32x32x32_i8(A0, B1, acc01, 0, 0, 0);
        acc10 = __builtin_amdgcn_mfma_i32_32x32x32_i8(A1, B0, acc10, 0, 0, 0);
        acc11 = __builtin_amdgcn_mfma_i32_32x32x32_i8(A1, B1, acc11, 0, 0, 0);
    }

    __syncthreads();   // ldsB free -> reuse as transpose scratch

    // ---- epilogue: alpha-scale + wave-private LDS transpose (R12-validated) --
    float* tlw = (float*)ldsB + wid * (32 * 33);   // 8 waves x 4224 B
    float alf0 = alpha[ocb + l31];
    float alf1 = alpha[ocb + 32 + l31];

#pragma unroll
    for (int tm = 0; tm < 2; ++tm) {
#pragma unroll
        for (int tn = 0; tn < 2; ++tn) {
            const v16i* ac = tm ? (tn ? &acc11 : &acc10) : (tn ? &acc01 : &acc00);
            float alf = tn ? alf1 : alf0;
            // C layout: col(oc)=lane&31, row(px)=(r&3)+8*(r>>2)+4*half
#pragma unroll
            for (int r = 0; r < 16; ++r) {
                int row = (r & 3) + 8 * (r >> 2) + 4 * half;
                tlw[row * 33 + l31] = (float)(*ac)[r] * alf;
            }
            // wave-synchronous transpose read: lane -> (px=l31, oc=2r+half)
#pragma unroll
            for (int r = 0; r < 16; ++r) {
                float v = tlw[l31 * 33 + 2 * r + half];
                int oc = ocb + tn * 32 + 2 * r;
                out[ob[tm] + (size_t)oc * HWSZ] = v;
            }
        }
    }
}

// ===========================================================================
// ================== bitplane fallback path (verified R5) ===================
// ===========================================================================

__global__ void __launch_bounds__(256) wpack32_kernel(
    const float* __restrict__ M, const float* __restrict__ Z,
    const float* __restrict__ rv, uint32_t* __restrict__ wpk32) {
    int gtid = blockIdx.x * blockDim.x + threadIdx.x;
    int lane = gtid & 63;
    int wid  = gtid >> 6;
    int oc   = wid / 18;
    int r    = wid - oc * 18;
    int tap  = r >> 1;
    int word = r & 1;
    int ic   = word * 64 + lane;
    int idx  = (oc * IC + ic) * NTAP + tap;

    float m  = M[idx];
    float z0 = Z[0 * NWEL + idx];
    float z1 = Z[1 * NWEL + idx];
    float z2 = Z[2 * NWEL + idx];
    float z3 = Z[3 * NWEL + idx];
    float z4 = Z[4 * NWEL + idx];
    float s  = z0 * z0 + z1 * z1 + z2 * z2 + z3 * z3 + z4 * z4;
    float A  = m * m + s * (1.0f / SCALE_F);
    float inv = 1.0f / sqrtf(A);
    float w = rv[0] * (z0 * inv);
    w += rv[1] * (z1 * inv);
    w += rv[2] * (z2 * inv);
    w += rv[3] * (z3 * inv);
    w += rv[4] * (z4 * inv);
    w += m * inv;

    unsigned long long b = __ballot(w > 0.0f);
    if (lane == 0) {
        uint64_t* wpk = (uint64_t*)wpk32;
        wpk[(oc * NTAP + tap) * 2 + word] = b;
    }
}

__global__ void __launch_bounds__(256) apack32_kernel(
    const float* __restrict__ x, uint32_t* __restrict__ apk32) {
    int q  = blockIdx.x * blockDim.x + threadIdx.x;
    int wd = blockIdx.y;
    int n  = q / HWSZ;
    int hw = q - n * HWSZ;
    int h  = hw / WW;
    int w  = hw - h * WW;
    const float* xp = x + (size_t)n * IC * HWSZ + (size_t)wd * 32 * HWSZ + hw;

    uint32_t b = 0;
#pragma unroll
    for (int c = 0; c < 32; ++c)
        b |= (uint32_t)(xp[(size_t)c * HWSZ] > 0.0f) << c;

    apk32[(size_t)wd * PLSTRIDE + (size_t)n * PLANE + (size_t)(h + 1) * PW + (w + 1)] = b;
}

__global__ void __launch_bounds__(256, 8) bconv32_kernel(
    const uint32_t* __restrict__ apk32, const uint32_t* __restrict__ wpk32,
    const float* __restrict__ alpha, float* __restrict__ out) {
    __shared__ int adj[OCPB][9];
    __shared__ float alf[OCPB];

    int tx  = threadIdx.x;
    int oc0 = blockIdx.y * OCPB;

    if (tx < OCPB) alf[tx] = alpha[oc0 + tx];
    if (tx < OCPB * 9) {
        int ocl = tx / 9, cls = tx % 9;
        int rc = cls / 3, cc = cls % 3;
        int nv = ((rc == 1) ? 3 : 2) * ((cc == 1) ? 3 : 2);
        int s = 0;
#pragma unroll
        for (int t = 0; t < NTAP; ++t) {
            int i = t / 3, j = t % 3;
            bool invld = (rc == 0 && i == 0) || (rc == 2 && i == 2) ||
                         (cc == 0 && j == 0) || (cc == 2 && j == 2);
            if (invld) {
                const uint64_t* wpk = (const uint64_t*)wpk32;
                uint64_t lo = wpk[(oc0 + ocl) * NTAP * 2 + t * 2 + 0];
                uint64_t hi = wpk[(oc0 + ocl) * NTAP * 2 + t * 2 + 1];
                s += __popcll(lo) + __popcll(hi);
            }
        }
        adj[ocl][cls] = 128 * nv + 2 * s;
    }
    __syncthreads();

    int t  = blockIdx.x * blockDim.x + tx;
    int sw = t % 14;
    int h  = (t / 14) % HH;
    int n  = t / (14 * HH);
    int w0 = sw * WPT;

    const uint32_t* ap = apk32 + (size_t)n * PLANE + (size_t)h * PW + w0;
    const uint64_t* wpk = (const uint64_t*)wpk32;

    int cnt[WPT * OCPB] = {0};
#pragma unroll 1
    for (int r = 0; r < 3; ++r) {
#pragma unroll 1
        for (int wd = 0; wd < 4; ++wd) {
            const uint32_t* p = ap + (size_t)wd * PLSTRIDE + (size_t)r * PW;
            uint32_t T[6];
#pragma unroll
            for (int c = 0; c < 6; ++c) T[c] = p[c];
#pragma unroll
            for (int j = 0; j < 3; ++j) {
#pragma unroll
                for (int ocl = 0; ocl < OCPB; ++ocl) {
                    uint64_t w2 = wpk[(oc0 + ocl) * NTAP * 2 + (r * 3 + j) * 2 + (wd >> 1)];
                    uint32_t wv = (wd & 1) ? (uint32_t)(w2 >> 32) : (uint32_t)w2;
#pragma unroll
                    for (int o = 0; o < WPT; ++o)
                        cnt[o * OCPB + ocl] += __popc(T[j + o] ^ wv);
                }
            }
        }
    }

    int rcls = (h == 0) ? 0 : ((h == HH - 1) ? 6 : 3);
    int clsL = rcls + ((w0 == 0) ? 0 : 1);
    int clsI = rcls + 1;
    int clsR = rcls + ((w0 == WW - WPT) ? 2 : 1);
    float* op = out + ((size_t)n * OC + oc0) * HWSZ + h * WW + w0;
#pragma unroll
    for (int ocl = 0; ocl < OCPB; ++ocl) {
        float a = alf[ocl];
        float4 v;
        v.x = (float)(adj[ocl][clsL] - 2 * cnt[0 * OCPB + ocl]) * a;
        v.y = (float)(adj[ocl][clsI] - 2 * cnt[1 * OCPB + ocl]) * a;
        v.z = (float)(adj[ocl][clsI] - 2 * cnt[2 * OCPB + ocl]) * a;
        v.w = (float)(adj[ocl][clsR] - 2 * cnt[3 * OCPB + ocl]) * a;
        *(float4*)(op + (size_t)ocl * HWSZ) = v;
    }
}

extern "C" void kernel_launch(void* const* d_in, const int* in_sizes, int n_in,
                              void* d_out, int out_size, void* d_ws, size_t ws_size,
                              hipStream_t stream) {
    const float* x     = (const float*)d_in[0];
    const float* M     = (const float*)d_in[1];
    const float* Z     = (const float*)d_in[2];
    const float* Alpha = (const float*)d_in[3];
    const float* rv    = (const float*)d_in[4];
    float* out = (float*)d_out;

    const size_t mfma_needed = 196608 + (size_t)NB * PD * NICQ * PD * 16 + (1 << 20);

    if (ws_size >= mfma_needed) {
        int8_t* bfrag = (int8_t*)d_ws;                      // 147,456 B
        int8_t* apk8  = (int8_t*)d_ws + 196608;             // 27,557,888 B

        border_kernel<<<(NB * 1824) / 256, 256, 0, stream>>>(apk8);
        wpack_kernel<<<NWEL / 256, 256, 0, stream>>>(M, Z, rv, bfrag);
        apack_kernel<<<dim3(HH, NB), 448, 0, stream>>>(x, apk8);
        bconv_kernel<<<784, 512, 0, stream>>>(apk8, bfrag, Alpha, out);
    } else {
        // verified bitplane fallback (R5)
        uint32_t* wpk32 = (uint32_t*)d_ws;                  // 18,432 B
        uint32_t* apk32 = (uint32_t*)((char*)d_ws + 32768); // 3,563,520 B

        hipMemsetAsync(apk32, 0, (size_t)4 * PLSTRIDE * 4, stream);
        wpack32_kernel<<<NWEL / 256, 256, 0, stream>>>(M, Z, rv, wpk32);
        apack32_kernel<<<dim3((NB * HWSZ) / 256, 4), 256, 0, stream>>>(x, apk32);
        bconv32_kernel<<<dim3((NB * HH * 14) / 256, OC / OCPB), 256, 0, stream>>>(
            apk32, wpk32, Alpha, out);
    }
}

// Round 23
// 78.901 us; speedup vs baseline: 1.0079x; 1.0079x over previous
//
#include <hip/hip_runtime.h>
#include <stdint.h>

#define KK 5
#define SCALE_F 50000.0f
#define OC 128
#define IC 128
#define HH 56
#define WW 56
#define NB 64
#define HWSZ (HH * WW)          // 3136
#define NTAP 9
#define NWEL (OC * IC * NTAP)   // 147456

// ---- MFMA path geometry ----
#define PD 58                   // padded spatial dim
#define NICQ 8                  // 16-byte ic-chunks per pixel (128 ic)
// apk8 chunk index: ((n*PD + hh)*NICQ + icq)*PD + ww ; byte addr = chunk*16
// bfrag chunk index: (kk*4 + oct)*64 + lane   (kk = icb*9 + tap)

// ---- bitplane fallback geometry (verified R5) ----
#define PW 60
#define PROWS 58
#define PLANE (PROWS * PW)      // 3480
#define PLSTRIDE (NB * PLANE)   // 222720
#define OCPB 2
#define WPT 4

typedef int v4i  __attribute__((ext_vector_type(4)));
typedef int v16i __attribute__((ext_vector_type(16)));

__device__ __forceinline__ constexpr int koff2(int kk) {
    int icb = kk / 9, tap = kk % 9;
    int dh = tap / 3 - 1, dw = tap % 3 - 1;
    return (dh * NICQ + icb * 2) * PD + dw;
}

// ===========================================================================
// ============================ MFMA (primary) path ==========================
// ===========================================================================

// Kernel 0: zero the padded borders of apk8 (1824 chunks per n).
__global__ void __launch_bounds__(256) border_kernel(int8_t* __restrict__ apk8) {
    int j = blockIdx.x * 256 + threadIdx.x;       // < 64*1824 = 116736
    int n  = j / 1824;
    int rj = j - n * 1824;
    int hh, icq, ww;
    if (rj < 928) {                                // rows 0 and 57
        hh = (rj / 464) * 57;
        int q = rj % 464;
        icq = q / PD;
        ww  = q - icq * PD;
    } else {                                       // cols 0 and 57, rows 1..56
        int q = rj - 928;                          // < 896
        hh = 1 + (q >> 4);
        int r2 = q & 15;
        icq = r2 >> 1;
        ww  = (r2 & 1) * 57;
    }
    size_t chunk = (((size_t)n * PD + hh) * NICQ + icq) * PD + ww;
    *(int4*)(apk8 + chunk * 16) = make_int4(0, 0, 0, 0);
}

// Kernel 1: SDP weight gen + binarize; int8 +-1 in MFMA B-fragment order.
__global__ void __launch_bounds__(256) wpack_kernel(
    const float* __restrict__ M, const float* __restrict__ Z,
    const float* __restrict__ rv, int8_t* __restrict__ bfrag) {
    int i = blockIdx.x * 256 + threadIdx.x;       // < 147456
    int oc = i / 1152;
    int r1 = i - oc * 1152;
    int ic = r1 / 9;
    int tap = r1 - ic * 9;

    float m  = M[i];
    float z0 = Z[0 * NWEL + i];
    float z1 = Z[1 * NWEL + i];
    float z2 = Z[2 * NWEL + i];
    float z3 = Z[3 * NWEL + i];
    float z4 = Z[4 * NWEL + i];
    float s  = z0 * z0 + z1 * z1 + z2 * z2 + z3 * z3 + z4 * z4;
    float A  = m * m + s * (1.0f / SCALE_F);
    float inv = 1.0f / sqrtf(A);
    float w = rv[0] * (z0 * inv);
    w += rv[1] * (z1 * inv);
    w += rv[2] * (z2 * inv);
    w += rv[3] * (z3 * inv);
    w += rv[4] * (z4 * inv);
    w += m * inv;

    int8_t sv = (w > 0.0f) ? (int8_t)1 : (int8_t)-1;
    int icb = ic >> 5, khalf = (ic >> 4) & 1, b = ic & 15;
    int kk  = icb * 9 + tap;                      // K order matches bconv
    int oct = oc >> 5;
    int lane = khalf * 32 + (oc & 31);
    bfrag[(size_t)((kk * 4 + oct) * 64 + lane) * 16 + b] = sv;
}

// Kernel 2: binarize f32 NCHW -> int8 chunked layout [n][hh][icq][ww][16].
__global__ void __launch_bounds__(448) apack_kernel(
    const float* __restrict__ x, int8_t* __restrict__ apk8) {
    int h = blockIdx.x;           // 0..55
    int n = blockIdx.y;           // 0..63
    int t = threadIdx.x;          // 0..447
    int w   = t % 56;
    int icq = t / 56;             // 0..7
    const float* xp = x + ((size_t)n * IC + icq * 16) * HWSZ + h * WW + w;

    uint32_t pk[4];
#pragma unroll
    for (int g = 0; g < 4; ++g) {
        uint32_t v = 0;
#pragma unroll
        for (int j = 0; j < 4; ++j) {
            float f = xp[(size_t)(g * 4 + j) * HWSZ];
            uint32_t sel = (f > 0.0f) ? 0x01u : 0xFFu;
            v |= sel << (8 * j);
        }
        pk[g] = v;
    }
    size_t chunk = (((size_t)n * PD + (h + 1)) * NICQ + icq) * PD + (w + 1);
    *(uint4*)(apk8 + chunk * 16) = make_uint4(pk[0], pk[1], pk[2], pk[3]);
}

// A-load via inline asm: INVISIBLE to the compiler's waitcnt tracker, so the
// only vmcnt waits in the K-loop are OUR counted ones (AITER pattern, T4).
#define ALOAD(slot, kkp)                                                     \
    asm volatile("global_load_dwordx4 %0, %1, off"                           \
                 : "=v"(ar[slot])                                            \
                 : "v"((uint64_t)(uintptr_t)(apk8 + ((size_t)(ab0 + koff2(kkp)) << 4))))
#define TBLOAD(dst, idx, kkp, j)                                             \
    asm volatile("global_load_dwordx4 %0, %1, off"                           \
                 : "=v"(dst[idx])                                            \
                 : "v"((uint64_t)(uintptr_t)(bfrag + ((size_t)((((kkp) << 2) + (och << 1) + (j)) * 64 + lane) << 4))))

// Kernel 3: implicit-GEMM conv — R21 + EXACTLY 64 KB LDS (occupancy probe).
// Identical shell to R21 (grid 1568, 512 thr = 8 waves, wave = 32 px x 64 oc,
// counted asm vmcnt). CHANGE: ldsB holds only kk 0..31 (65,536 B exactly);
// B for kk 32..35 comes from 8 asm global loads issued FIRST post-barrier
// (in-order vmcnt completion => provably landed before kk=32, where our
// counted waits have drained outstanding to <= 3). Hypothesis under test:
// 73.7 KB LDS was rounding past the 2-block boundary (measured 27% occ);
// 64 KB x 2 = 128 <= 160 KB => 2 blocks/CU = 2x wave concurrency.
__global__ void __launch_bounds__(512, 4) bconv_kernel(
    const int8_t* __restrict__ apk8, const int8_t* __restrict__ bfrag,
    const float* __restrict__ alpha, float* __restrict__ out) {
    __shared__ uint4 ldsB[4096];   // [kk32][j2][lane64], 65,536 B exactly

    int tx = threadIdx.x;
    int lane = tx & 63, wid = tx >> 6;        // wid 0..7
    int half = lane >> 5, l31 = lane & 31;

    // bijective XCD swizzle (1568 = 8 * 196); och pairs colocate per XCD
    int bid = blockIdx.x;
    int swz = (bid & 7) * 196 + (bid >> 3);    // 0..1567
    int och = swz & 1;
    int pxb = swz >> 1;                        // 0..783
    int ocb = och * 64;

    int px = pxb * 256 + wid * 32 + l31;       // < 200704 exactly
    int n  = px / HWSZ;
    int hw = px - n * HWSZ;
    int h  = hw / WW;
    int w  = hw - h * WW;
    int ab0 = ((n * PD + h + 1) * NICQ + half) * PD + (w + 1);
    size_t ob0 = ((size_t)n * OC + ocb + half) * HWSZ + hw;

    // ---- A ring-6: issue A0..A4 BEFORE B staging (drained by the barrier,
    // values land in regs; no in-loop wait needed for kk < 5) ----
    v4i ar[6];
    ALOAD(0, 0); ALOAD(1, 1); ALOAD(2, 2); ALOAD(3, 3); ALOAD(4, 4);

    // ---- stage B kk 0..31: 4096 chunks, 8 per thread, coalesced ----
    const uint4* gB = (const uint4*)bfrag;
#pragma unroll
    for (int s = 0; s < 8; ++s) {
        int idx = tx + s * 512;
        int kk = idx >> 7, j = (idx >> 6) & 1, ln = idx & 63;
        ldsB[idx] = gB[((kk << 2) + (och << 1) + j) * 64 + ln];
    }
    __syncthreads();   // vmcnt(0) drain: prologue A + staging all complete

    // ---- tail B (kk 32..35): 8 asm loads, FIRST in post-barrier stream ----
    v4i tb0[4], tb1[4];
    TBLOAD(tb0, 0, 32, 0); TBLOAD(tb1, 0, 32, 1);
    TBLOAD(tb0, 1, 33, 0); TBLOAD(tb1, 1, 33, 1);
    TBLOAD(tb0, 2, 34, 0); TBLOAD(tb1, 2, 34, 1);
    TBLOAD(tb0, 3, 35, 0); TBLOAD(tb1, 3, 35, 1);

    // ---- B ring-2: preload kk = 0 (compiler-tracked lgkmcnt) ----
    v4i b0r[2], b1r[2];
    b0r[0] = *(const v4i*)&ldsB[0 * 128 + lane];
    b1r[0] = *(const v4i*)&ldsB[0 * 128 + 64 + lane];

    v16i acc0 = {}, acc1 = {};
#pragma unroll
    for (int kk = 0; kk < 36; ++kk) {
        if (kk + 5 < 36) ALOAD((kk + 5) % 6, kk + 5);   // issue 5 ahead

        // counted wait (A[kk] = post-barrier load #(kk+4) for kk>=5;
        // 8 tb loads precede the A stream and complete first, in order)
        if (kk >= 5) {
            if (kk <= 30)      asm volatile("s_waitcnt vmcnt(5)");
            else if (kk == 31) asm volatile("s_waitcnt vmcnt(4)");
            else if (kk == 32) asm volatile("s_waitcnt vmcnt(3)");
            else if (kk == 33) asm volatile("s_waitcnt vmcnt(2)");
            else if (kk == 34) asm volatile("s_waitcnt vmcnt(1)");
            else               asm volatile("s_waitcnt vmcnt(0)");
            __builtin_amdgcn_sched_barrier(0);   // rule #18
        }

        if (kk + 1 < 32) {                   // B prefetch, 1 ahead (LDS part)
            b0r[(kk + 1) & 1] = *(const v4i*)&ldsB[(kk + 1) * 128 + lane];
            b1r[(kk + 1) & 1] = *(const v4i*)&ldsB[(kk + 1) * 128 + 64 + lane];
        }
        v4i A  = ar[kk % 6];
        v4i B0 = (kk < 32) ? b0r[kk & 1] : tb0[kk - 32];   // static after unroll
        v4i B1 = (kk < 32) ? b1r[kk & 1] : tb1[kk - 32];
        acc0 = __builtin_amdgcn_mfma_i32_32x32x32_i8(A, B0, acc0, 0, 0, 0);
        acc1 = __builtin_amdgcn_mfma_i32_32x32x32_i8(A, B1, acc1, 0, 0, 0);
    }

    __syncthreads();   // ldsB free -> reuse as transpose scratch (33.8 KB)

    // ---- epilogue: alpha-scale + wave-private LDS transpose (validated) ----
    float* tlw = (float*)ldsB + wid * (32 * 33);   // 8 waves x 4224 B
    float alf0 = alpha[ocb + l31];
    float alf1 = alpha[ocb + 32 + l31];

#pragma unroll
    for (int tn = 0; tn < 2; ++tn) {
        const v16i* ac = tn ? &acc1 : &acc0;
        float alf = tn ? alf1 : alf0;
        // C layout: col(oc)=lane&31, row(px)=(r&3)+8*(r>>2)+4*half
#pragma unroll
        for (int r = 0; r < 16; ++r) {
            int row = (r & 3) + 8 * (r >> 2) + 4 * half;
            tlw[row * 33 + l31] = (float)(*ac)[r] * alf;
        }
        // wave-synchronous transpose read: lane -> (px=l31, oc=2r+half)
#pragma unroll
        for (int r = 0; r < 16; ++r) {
            float v = tlw[l31 * 33 + 2 * r + half];
            out[ob0 + (size_t)(tn * 32 + 2 * r) * HWSZ] = v;
        }
    }
}

// ===========================================================================
// ================== bitplane fallback path (verified R5) ===================
// ===========================================================================

__global__ void __launch_bounds__(256) wpack32_kernel(
    const float* __restrict__ M, const float* __restrict__ Z,
    const float* __restrict__ rv, uint32_t* __restrict__ wpk32) {
    int gtid = blockIdx.x * blockDim.x + threadIdx.x;
    int lane = gtid & 63;
    int wid  = gtid >> 6;
    int oc   = wid / 18;
    int r    = wid - oc * 18;
    int tap  = r >> 1;
    int word = r & 1;
    int ic   = word * 64 + lane;
    int idx  = (oc * IC + ic) * NTAP + tap;

    float m  = M[idx];
    float z0 = Z[0 * NWEL + idx];
    float z1 = Z[1 * NWEL + idx];
    float z2 = Z[2 * NWEL + idx];
    float z3 = Z[3 * NWEL + idx];
    float z4 = Z[4 * NWEL + idx];
    float s  = z0 * z0 + z1 * z1 + z2 * z2 + z3 * z3 + z4 * z4;
    float A  = m * m + s * (1.0f / SCALE_F);
    float inv = 1.0f / sqrtf(A);
    float w = rv[0] * (z0 * inv);
    w += rv[1] * (z1 * inv);
    w += rv[2] * (z2 * inv);
    w += rv[3] * (z3 * inv);
    w += rv[4] * (z4 * inv);
    w += m * inv;

    unsigned long long b = __ballot(w > 0.0f);
    if (lane == 0) {
        uint64_t* wpk = (uint64_t*)wpk32;
        wpk[(oc * NTAP + tap) * 2 + word] = b;
    }
}

__global__ void __launch_bounds__(256) apack32_kernel(
    const float* __restrict__ x, uint32_t* __restrict__ apk32) {
    int q  = blockIdx.x * blockDim.x + threadIdx.x;
    int wd = blockIdx.y;
    int n  = q / HWSZ;
    int hw = q - n * HWSZ;
    int h  = hw / WW;
    int w  = hw - h * WW;
    const float* xp = x + (size_t)n * IC * HWSZ + (size_t)wd * 32 * HWSZ + hw;

    uint32_t b = 0;
#pragma unroll
    for (int c = 0; c < 32; ++c)
        b |= (uint32_t)(xp[(size_t)c * HWSZ] > 0.0f) << c;

    apk32[(size_t)wd * PLSTRIDE + (size_t)n * PLANE + (size_t)(h + 1) * PW + (w + 1)] = b;
}

__global__ void __launch_bounds__(256, 8) bconv32_kernel(
    const uint32_t* __restrict__ apk32, const uint32_t* __restrict__ wpk32,
    const float* __restrict__ alpha, float* __restrict__ out) {
    __shared__ int adj[OCPB][9];
    __shared__ float alf[OCPB];

    int tx  = threadIdx.x;
    int oc0 = blockIdx.y * OCPB;

    if (tx < OCPB) alf[tx] = alpha[oc0 + tx];
    if (tx < OCPB * 9) {
        int ocl = tx / 9, cls = tx % 9;
        int rc = cls / 3, cc = cls % 3;
        int nv = ((rc == 1) ? 3 : 2) * ((cc == 1) ? 3 : 2);
        int s = 0;
#pragma unroll
        for (int t = 0; t < NTAP; ++t) {
            int i = t / 3, j = t % 3;
            bool invld = (rc == 0 && i == 0) || (rc == 2 && i == 2) ||
                         (cc == 0 && j == 0) || (cc == 2 && j == 2);
            if (invld) {
                const uint64_t* wpk = (const uint64_t*)wpk32;
                uint64_t lo = wpk[(oc0 + ocl) * NTAP * 2 + t * 2 + 0];
                uint64_t hi = wpk[(oc0 + ocl) * NTAP * 2 + t * 2 + 1];
                s += __popcll(lo) + __popcll(hi);
            }
        }
        adj[ocl][cls] = 128 * nv + 2 * s;
    }
    __syncthreads();

    int t  = blockIdx.x * blockDim.x + tx;
    int sw = t % 14;
    int h  = (t / 14) % HH;
    int n  = t / (14 * HH);
    int w0 = sw * WPT;

    const uint32_t* ap = apk32 + (size_t)n * PLANE + (size_t)h * PW + w0;
    const uint64_t* wpk = (const uint64_t*)wpk32;

    int cnt[WPT * OCPB] = {0};
#pragma unroll 1
    for (int r = 0; r < 3; ++r) {
#pragma unroll 1
        for (int wd = 0; wd < 4; ++wd) {
            const uint32_t* p = ap + (size_t)wd * PLSTRIDE + (size_t)r * PW;
            uint32_t T[6];
#pragma unroll
            for (int c = 0; c < 6; ++c) T[c] = p[c];
#pragma unroll
            for (int j = 0; j < 3; ++j) {
#pragma unroll
                for (int ocl = 0; ocl < OCPB; ++ocl) {
                    uint64_t w2 = wpk[(oc0 + ocl) * NTAP * 2 + (r * 3 + j) * 2 + (wd >> 1)];
                    uint32_t wv = (wd & 1) ? (uint32_t)(w2 >> 32) : (uint32_t)w2;
#pragma unroll
                    for (int o = 0; o < WPT; ++o)
                        cnt[o * OCPB + ocl] += __popc(T[j + o] ^ wv);
                }
            }
        }
    }

    int rcls = (h == 0) ? 0 : ((h == HH - 1) ? 6 : 3);
    int clsL = rcls + ((w0 == 0) ? 0 : 1);
    int clsI = rcls + 1;
    int clsR = rcls + ((w0 == WW - WPT) ? 2 : 1);
    float* op = out + ((size_t)n * OC + oc0) * HWSZ + h * WW + w0;
#pragma unroll
    for (int ocl = 0; ocl < OCPB; ++ocl) {
        float a = alf[ocl];
        float4 v;
        v.x = (float)(adj[ocl][clsL] - 2 * cnt[0 * OCPB + ocl]) * a;
        v.y = (float)(adj[ocl][clsI] - 2 * cnt[1 * OCPB + ocl]) * a;
        v.z = (float)(adj[ocl][clsI] - 2 * cnt[2 * OCPB + ocl]) * a;
        v.w = (float)(adj[ocl][clsR] - 2 * cnt[3 * OCPB + ocl]) * a;
        *(float4*)(op + (size_t)ocl * HWSZ) = v;
    }
}

extern "C" void kernel_launch(void* const* d_in, const int* in_sizes, int n_in,
                              void* d_out, int out_size, void* d_ws, size_t ws_size,
                              hipStream_t stream) {
    const float* x     = (const float*)d_in[0];
    const float* M     = (const float*)d_in[1];
    const float* Z     = (const float*)d_in[2];
    const float* Alpha = (const float*)d_in[3];
    const float* rv    = (const float*)d_in[4];
    float* out = (float*)d_out;

    const size_t mfma_needed = 196608 + (size_t)NB * PD * NICQ * PD * 16 + (1 << 20);

    if (ws_size >= mfma_needed) {
        int8_t* bfrag = (int8_t*)d_ws;                      // 147,456 B
        int8_t* apk8  = (int8_t*)d_ws + 196608;             // 27,557,888 B

        border_kernel<<<(NB * 1824) / 256, 256, 0, stream>>>(apk8);
        wpack_kernel<<<NWEL / 256, 256, 0, stream>>>(M, Z, rv, bfrag);
        apack_kernel<<<dim3(HH, NB), 448, 0, stream>>>(x, apk8);
        bconv_kernel<<<1568, 512, 0, stream>>>(apk8, bfrag, Alpha, out);
    } else {
        // verified bitplane fallback (R5)
        uint32_t* wpk32 = (uint32_t*)d_ws;                  // 18,432 B
        uint32_t* apk32 = (uint32_t*)((char*)d_ws + 32768); // 3,563,520 B

        hipMemsetAsync(apk32, 0, (size_t)4 * PLSTRIDE * 4, stream);
        wpack32_kernel<<<NWEL / 256, 256, 0, stream>>>(M, Z, rv, wpk32);
        apack32_kernel<<<dim3((NB * HWSZ) / 256, 4), 256, 0, stream>>>(x, apk32);
        bconv32_kernel<<<dim3((NB * HH * 14) / 256, OC / OCPB), 256, 0, stream>>>(
            apk32, wpk32, Alpha, out);
    }
}